// Round 5
// baseline (1753.051 us; speedup 1.0000x reference)
//
#include <hip/hip_runtime.h>

// All fp32: reference dtypes are float32 in and out.
// mnT: layernormed input stored TRANSPOSED [l, s, cm] (l=seq_len pos, s=n_seq).
// osc: attention output already permuted through the reference's raw reshape,
//      stored [s_o, l_o, hc] = [65536, 256] fp32.

// ---- K1: LayerNorm over c_m; row = s*256+l; writes mnT[l,s,:] ----
__global__ __launch_bounds__(256) void k_ln(const float* __restrict__ m,
    const float* __restrict__ lw, const float* __restrict__ lb,
    float* __restrict__ mnT){
  int row = blockIdx.x;            // s*256 + l
  int s = row>>8, l = row&255;
  int tid = threadIdx.x;
  float x = m[(size_t)row*256 + tid];
  float s1 = x, s2 = x*x;
  #pragma unroll
  for (int off=32; off>0; off>>=1){
    s1 += __shfl_down(s1, off);
    s2 += __shfl_down(s2, off);
  }
  __shared__ float red[10];
  int wv = tid>>6, ln = tid&63;
  if (ln==0){ red[wv]=s1; red[4+wv]=s2; }
  __syncthreads();
  if (tid==0){
    float a = red[0]+red[1]+red[2]+red[3];
    float c = red[4]+red[5]+red[6]+red[7];
    float mu  = a*(1.0f/256.0f);
    float var = c*(1.0f/256.0f) - mu*mu;
    red[8]=mu; red[9]=rsqrtf(var + 1e-5f);
  }
  __syncthreads();
  float mu=red[8], inv=red[9];
  mnT[((size_t)l*256 + s)*256 + tid] = (x-mu)*inv*lw[tid] + lb[tid];
}

// ---- K2: fused per-(l,h) QKV projection + attention over n_seq ----
// bx = l*8 + h. Thread t owns query row s=t.
// q[s,c] = sum_cm mn[s,l,cm] * wq[cm, h*32+c]   (mn[s,l,:] == mnT[l,s,:])
__global__ __launch_bounds__(256) void k_attn_f(const float* __restrict__ mnT,
    const float* __restrict__ wq, const float* __restrict__ wk,
    const float* __restrict__ wv, float* __restrict__ osc){
  __shared__ float Ks[256*32];     // 32 KB
  __shared__ float Vs[256*32];     // 32 KB
  int bx = blockIdx.x;
  int l = bx>>3, h = bx&7;
  int t = threadIdx.x;
  float qa[32], ka[32], va[32];
  #pragma unroll
  for (int c=0;c<32;++c){ qa[c]=0.f; ka[c]=0.f; va[c]=0.f; }
  const float* mrow = mnT + ((size_t)l*256 + t)*256;   // mn[s=t, l, :]
  int wofs = h*32;
  for (int cm0=0; cm0<256; cm0+=4){
    float4 xv = *(const float4*)&mrow[cm0];
    float xx[4] = { xv.x, xv.y, xv.z, xv.w };
    #pragma unroll
    for (int j=0;j<4;++j){
      int cm = cm0+j;
      float x = xx[j];
      const float4* q4 = (const float4*)&wq[cm*256 + wofs];
      #pragma unroll
      for (int g=0; g<8; ++g){
        float4 a = q4[g];
        qa[g*4+0]+=x*a.x; qa[g*4+1]+=x*a.y; qa[g*4+2]+=x*a.z; qa[g*4+3]+=x*a.w;
      }
      const float4* k4 = (const float4*)&wk[cm*256 + wofs];
      #pragma unroll
      for (int g=0; g<8; ++g){
        float4 a = k4[g];
        ka[g*4+0]+=x*a.x; ka[g*4+1]+=x*a.y; ka[g*4+2]+=x*a.z; ka[g*4+3]+=x*a.w;
      }
      const float4* v4 = (const float4*)&wv[cm*256 + wofs];
      #pragma unroll
      for (int g=0; g<8; ++g){
        float4 a = v4[g];
        va[g*4+0]+=x*a.x; va[g*4+1]+=x*a.y; va[g*4+2]+=x*a.z; va[g*4+3]+=x*a.w;
      }
    }
  }
  #pragma unroll
  for (int g=0; g<8; ++g){
    *(float4*)&Ks[t*32+g*4] = make_float4(ka[g*4+0],ka[g*4+1],ka[g*4+2],ka[g*4+3]);
    *(float4*)&Vs[t*32+g*4] = make_float4(va[g*4+0],va[g*4+1],va[g*4+2],va[g*4+3]);
  }
  __syncthreads();

  const float scale = 0.17677669529663687f;  // 1/sqrt(32)
  float mx = -1.0e30f, ls = 0.f;
  float o[32];
  #pragma unroll
  for (int c=0;c<32;++c) o[c]=0.f;
  for (int tt=0; tt<256; ++tt){
    const float4* kp = (const float4*)&Ks[tt*32];
    float d = 0.f;
    #pragma unroll
    for (int g=0; g<8; ++g){
      float4 kv = kp[g];
      d += qa[g*4+0]*kv.x + qa[g*4+1]*kv.y + qa[g*4+2]*kv.z + qa[g*4+3]*kv.w;
    }
    d *= scale;
    float mn2 = fmaxf(mx, d);
    float al = __expf(mx - mn2);
    float p  = __expf(d - mn2);
    ls = ls*al + p;
    const float4* vp = (const float4*)&Vs[tt*32];
    #pragma unroll
    for (int g=0; g<8; ++g){
      float4 vv = vp[g];
      o[g*4+0] = o[g*4+0]*al + p*vv.x;
      o[g*4+1] = o[g*4+1]*al + p*vv.y;
      o[g*4+2] = o[g*4+2]*al + p*vv.z;
      o[g*4+3] = o[g*4+3]*al + p*vv.w;
    }
    mx = mn2;
  }
  float inv = 1.f/ls;
  // raw-reshape scramble: flat [B,H,L,S,ch] read as [s_o, l_o, hc]
  int s  = t;
  int so = 32*h + (l>>3);
  int lo = (l&7)*32 + (s>>3);
  int hc0 = (s&7)*32;
  float* op = osc + ((size_t)so*256 + lo)*256 + hc0;
  #pragma unroll
  for (int g=0; g<8; ++g){
    ((float4*)op)[g] = make_float4(o[g*4+0]*inv, o[g*4+1]*inv,
                                   o[g*4+2]*inv, o[g*4+3]*inv);
  }
}

// ---- K3: fused gate GEMM + sigmoid gating + out-projection ----
// Row r = s*256+l of the [65536,256] matrices. Block = 64 consecutive rows
// (same s, l0..l0+63). out = (sigmoid(mn@wg+bg) * osc) @ wo + bo.
__global__ __launch_bounds__(256) void k_out(const float* __restrict__ mnT,
    const float* __restrict__ wg, const float* __restrict__ bg,
    const float* __restrict__ wo, const float* __restrict__ bo,
    const float* __restrict__ osc, float* __restrict__ outp){
  __shared__ float mns[64*256];    // 64 KB staged mn rows (fp32)
  __shared__ float gst[64][65];    // 16.6 KB gated k-tile
  int r0 = blockIdx.x*64;
  int s0 = r0>>8, l0 = r0&255;
  int tid = threadIdx.x;
  int tx = tid&15, ty = tid>>4;

  // stage mn rows: mns[rL][cm] = mnT[l0+rL, s0, cm]
  #pragma unroll
  for (int i=0;i<16;++i){
    int e  = i*256 + tid;          // float4 index
    int rL = e>>6, c4 = e&63;
    *(float4*)&mns[rL*256 + c4*4] =
        *(const float4*)&mnT[(((size_t)(l0+rL))*256 + s0)*256 + c4*4];
  }
  __syncthreads();

  float accC[4][16];
  #pragma unroll
  for (int tc=0; tc<4; ++tc){
    float4 bb = *(const float4*)&bo[tc*64 + tx*4];
    #pragma unroll
    for (int ii=0;ii<4;++ii){
      accC[ii][tc*4+0]=bb.x; accC[ii][tc*4+1]=bb.y;
      accC[ii][tc*4+2]=bb.z; accC[ii][tc*4+3]=bb.w;
    }
  }

  for (int c0=0; c0<256; c0+=64){   // gate col-tile == C k-tile
    int j0 = c0 + tx*4;
    float accB[4][4];
    #pragma unroll
    for (int i=0;i<4;++i){ accB[i][0]=0.f; accB[i][1]=0.f; accB[i][2]=0.f; accB[i][3]=0.f; }
    for (int k=0;k<256;++k){
      float4 w4 = *(const float4*)&wg[k*256 + j0];
      #pragma unroll
      for (int ii=0;ii<4;++ii){
        float xv = mns[(ty*4+ii)*256 + k];
        accB[ii][0]+=xv*w4.x; accB[ii][1]+=xv*w4.y;
        accB[ii][2]+=xv*w4.z; accB[ii][3]+=xv*w4.w;
      }
    }
    float4 bgv = *(const float4*)&bg[j0];
    float gt[4][4];
    #pragma unroll
    for (int ii=0;ii<4;++ii){
      int r = r0 + ty*4 + ii;
      float4 ov = *(const float4*)&osc[(size_t)r*256 + j0];
      gt[ii][0] = ov.x / (1.f + __expf(-(accB[ii][0]+bgv.x)));
      gt[ii][1] = ov.y / (1.f + __expf(-(accB[ii][1]+bgv.y)));
      gt[ii][2] = ov.z / (1.f + __expf(-(accB[ii][2]+bgv.z)));
      gt[ii][3] = ov.w / (1.f + __expf(-(accB[ii][3]+bgv.w)));
    }
    __syncthreads();   // previous gst consumers done
    #pragma unroll
    for (int ii=0;ii<4;++ii){
      gst[ty*4+ii][tx*4+0]=gt[ii][0]; gst[ty*4+ii][tx*4+1]=gt[ii][1];
      gst[ty*4+ii][tx*4+2]=gt[ii][2]; gst[ty*4+ii][tx*4+3]=gt[ii][3];
    }
    __syncthreads();   // tile visible
    for (int kk=0; kk<64; ++kk){
      int kG = c0 + kk;
      float xv0 = gst[ty*4+0][kk];
      float xv1 = gst[ty*4+1][kk];
      float xv2 = gst[ty*4+2][kk];
      float xv3 = gst[ty*4+3][kk];
      #pragma unroll
      for (int tc=0; tc<4; ++tc){
        float4 w4 = *(const float4*)&wo[kG*256 + tc*64 + tx*4];
        accC[0][tc*4+0]+=xv0*w4.x; accC[0][tc*4+1]+=xv0*w4.y; accC[0][tc*4+2]+=xv0*w4.z; accC[0][tc*4+3]+=xv0*w4.w;
        accC[1][tc*4+0]+=xv1*w4.x; accC[1][tc*4+1]+=xv1*w4.y; accC[1][tc*4+2]+=xv1*w4.z; accC[1][tc*4+3]+=xv1*w4.w;
        accC[2][tc*4+0]+=xv2*w4.x; accC[2][tc*4+1]+=xv2*w4.y; accC[2][tc*4+2]+=xv2*w4.z; accC[2][tc*4+3]+=xv2*w4.w;
        accC[3][tc*4+0]+=xv3*w4.x; accC[3][tc*4+1]+=xv3*w4.y; accC[3][tc*4+2]+=xv3*w4.z; accC[3][tc*4+3]+=xv3*w4.w;
      }
    }
  }
  #pragma unroll
  for (int ii=0;ii<4;++ii){
    size_t r = r0 + ty*4 + ii;
    #pragma unroll
    for (int tc=0; tc<4; ++tc){
      int j0 = tc*64 + tx*4;
      *(float4*)&outp[r*256 + j0] = make_float4(accC[ii][tc*4+0], accC[ii][tc*4+1],
                                                accC[ii][tc*4+2], accC[ii][tc*4+3]);
    }
  }
}

extern "C" void kernel_launch(void* const* d_in, const int* in_sizes, int n_in,
                              void* d_out, int out_size, void* d_ws, size_t ws_size,
                              hipStream_t stream){
  const float* m  = (const float*)d_in[0];
  const float* lw = (const float*)d_in[1];
  const float* lb = (const float*)d_in[2];
  const float* wq = (const float*)d_in[3];
  const float* wk = (const float*)d_in[4];
  const float* wv = (const float*)d_in[5];
  const float* wg = (const float*)d_in[6];
  const float* bg = (const float*)d_in[7];
  const float* wo = (const float*)d_in[8];
  const float* bo = (const float*)d_in[9];

  // ws: mnT fp32 [l,s,cm] 64 MB | osc fp32 [s_o,l_o,hc] 64 MB  (128 MB total)
  float* mnT = (float*)d_ws;
  float* osc = mnT + (size_t)16777216;
  float* out = (float*)d_out;

  k_ln    <<<65536, 256, 0, stream>>>(m, lw, lb, mnT);
  k_attn_f<<<2048,  256, 0, stream>>>(mnT, wq, wk, wv, osc);
  k_out   <<<1024,  256, 0, stream>>>(mnT, wg, bg, wo, bo, osc, out);
}

// Round 6
// 816.520 us; speedup vs baseline: 2.1470x; 2.1470x over previous
//
#include <hip/hip_runtime.h>

typedef unsigned short u16;
typedef __attribute__((ext_vector_type(8))) short bf16x8;   // 8 bf16 = 4 VGPR
typedef __attribute__((ext_vector_type(4))) float f32x4;

__device__ __forceinline__ float b2f(u16 u){ return __uint_as_float(((unsigned int)u)<<16); }
__device__ __forceinline__ u16 f2b(float f){
  unsigned int u = __float_as_uint(f);
  u += 0x7fffu + ((u>>16)&1u);          // round-to-nearest-even
  return (u16)(u>>16);
}

// ---- K1: LayerNorm over c_m -> bf16 mnb [l, s, cm] ----
__global__ __launch_bounds__(256) void k_ln(const float* __restrict__ m,
    const float* __restrict__ lw, const float* __restrict__ lb,
    u16* __restrict__ mnb){
  int row = blockIdx.x;            // s*256 + l
  int s = row>>8, l = row&255;
  int tid = threadIdx.x;
  float x = m[(size_t)row*256 + tid];
  float s1 = x, s2 = x*x;
  #pragma unroll
  for (int off=32; off>0; off>>=1){
    s1 += __shfl_down(s1, off);
    s2 += __shfl_down(s2, off);
  }
  __shared__ float red[10];
  int wv = tid>>6, ln = tid&63;
  if (ln==0){ red[wv]=s1; red[4+wv]=s2; }
  __syncthreads();
  if (tid==0){
    float a = red[0]+red[1]+red[2]+red[3];
    float c = red[4]+red[5]+red[6]+red[7];
    float mu  = a*(1.0f/256.0f);
    float var = c*(1.0f/256.0f) - mu*mu;
    red[8]=mu; red[9]=rsqrtf(var + 1e-5f);
  }
  __syncthreads();
  float mu=red[8], inv=red[9];
  mnb[((size_t)l*256 + s)*256 + tid] = f2b((x-mu)*inv*lw[tid] + lb[tid]);
}

// ---- K2: MFMA QKV projection. grid (l=256, z=3, nhalf=2) ----
// Y[z][l][s][hc] = sum_cm mnb[l][s][cm] * W[cm][hc], bf16 out.
__global__ __launch_bounds__(256,2) void k_qkv(const u16* __restrict__ mnb,
    const float* __restrict__ wq, const float* __restrict__ wk,
    const float* __restrict__ wv,
    u16* __restrict__ Yq, u16* __restrict__ Yk, u16* __restrict__ Yv){
  __shared__ u16 WtS[128*264];     // W^T half: [n 128][cm 256], stride 264
  int l = blockIdx.x, z = blockIdx.y, n0 = blockIdx.z*128;
  const float* W = (z==0)?wq:(z==1)?wk:wv;
  u16* Y = (z==0)?Yq:(z==1)?Yk:Yv;
  int tid = threadIdx.x;
  int lane = tid&63, wid = tid>>6, quad = lane>>4, lo = lane&15;

  // stage W^T bf16 (thread: col n0+cidx, half the cm range)
  int cidx = tid&127, half = tid>>7;
  for (int i=0;i<16;++i){
    u16 tmp[8];
    #pragma unroll
    for (int j=0;j<8;++j){
      int cm = half*128 + i*8 + j;
      tmp[j] = f2b(W[cm*256 + n0 + cidx]);
    }
    *(ushort4*)&WtS[cidx*264 + half*128 + i*8]     = *(ushort4*)&tmp[0];
    *(ushort4*)&WtS[cidx*264 + half*128 + i*8 + 4] = *(ushort4*)&tmp[4];
  }
  __syncthreads();

  int m0 = wid*64;
  f32x4 acc[4][8];
  f32x4 z4 = {0.f,0.f,0.f,0.f};
  #pragma unroll
  for (int a=0;a<4;++a)
    #pragma unroll
    for (int b=0;b<8;++b) acc[a][b]=z4;

  const u16* Abase = mnb + (size_t)l*65536;
  for (int ks=0; ks<8; ++ks){
    bf16x8 af[4];
    #pragma unroll
    for (int mt=0; mt<4; ++mt)
      af[mt] = *(const bf16x8*)(Abase + (size_t)(m0+mt*16+lo)*256 + ks*32 + quad*8);
    bf16x8 bf[8];
    #pragma unroll
    for (int nt=0; nt<8; ++nt)
      bf[nt] = *(const bf16x8*)&WtS[(nt*16+lo)*264 + ks*32 + quad*8];
    #pragma unroll
    for (int mt=0; mt<4; ++mt)
      #pragma unroll
      for (int nt=0; nt<8; ++nt)
        acc[mt][nt] = __builtin_amdgcn_mfma_f32_16x16x32_bf16(af[mt], bf[nt], acc[mt][nt], 0,0,0);
  }
  // epilogue: C row = quad*4+reg, col = lane&15
  u16* Ybase = Y + (size_t)l*65536;
  #pragma unroll
  for (int mt=0; mt<4; ++mt)
    #pragma unroll
    for (int nt=0; nt<8; ++nt)
      #pragma unroll
      for (int r=0; r<4; ++r){
        int s  = m0 + mt*16 + quad*4 + r;
        int hc = n0 + nt*16 + lo;
        Ybase[(size_t)s*256 + hc] = f2b(acc[mt][nt][r]);
      }
}

// ---- K3: MFMA attention per (l,h); single pass, no max (|logit|<~10) ----
// writes fp32 scrambled output directly into d_out
__global__ __launch_bounds__(256,2) void k_attn(const u16* __restrict__ Yq,
    const u16* __restrict__ Yk, const u16* __restrict__ Yv,
    float* __restrict__ outp){
  __shared__ u16 VT[32*264];       // V^T [c 32][t 256] stride 264
  __shared__ u16 PB[4*64*40];      // per-wave P [64 m][32 t] stride 40
  int bx = blockIdx.x;
  int l = bx>>3, h = bx&7;
  int tid = threadIdx.x;
  int lane = tid&63, wid = tid>>6, quad = lane>>4, lo = lane&15;
  const size_t tile = ((size_t)l*256)*256 + h*32;
  const u16* qb = Yq + tile;
  const u16* kb = Yk + tile;
  const u16* vb = Yv + tile;

  // stage V^T: thread t reads V[t][0..31], writes VT[c][t]
  {
    int t = tid;
    const u16* vp = vb + (size_t)t*256;
    #pragma unroll
    for (int c4=0; c4<8; ++c4){
      ushort4 vv = *(const ushort4*)(vp + c4*4);
      VT[(c4*4+0)*264 + t] = vv.x;
      VT[(c4*4+1)*264 + t] = vv.y;
      VT[(c4*4+2)*264 + t] = vv.z;
      VT[(c4*4+3)*264 + t] = vv.w;
    }
  }

  int m0 = wid*64;
  int pbase = wid*64*40;
  // preload Q A-frags
  bf16x8 qf[4];
  #pragma unroll
  for (int mt=0; mt<4; ++mt)
    qf[mt] = *(const bf16x8*)(qb + (size_t)(m0+mt*16+lo)*256 + quad*8);

  __syncthreads();   // VT ready

  const float scale = 0.17677669529663687f;  // 1/sqrt(32)
  float lr[16];
  #pragma unroll
  for (int i=0;i<16;++i) lr[i]=0.f;
  f32x4 o_acc[4][2];
  f32x4 z4 = {0.f,0.f,0.f,0.f};
  #pragma unroll
  for (int a=0;a<4;++a){ o_acc[a][0]=z4; o_acc[a][1]=z4; }

  for (int ts=0; ts<8; ++ts){
    // S chunk: 4 m-tiles x 2 n-tiles (t = ts*32 + ntl*16 + lo)
    bf16x8 kf[2];
    #pragma unroll
    for (int ntl=0; ntl<2; ++ntl)
      kf[ntl] = *(const bf16x8*)(kb + (size_t)(ts*32+ntl*16+lo)*256 + quad*8);
    #pragma unroll
    for (int mt=0; mt<4; ++mt){
      #pragma unroll
      for (int ntl=0; ntl<2; ++ntl){
        f32x4 sa = __builtin_amdgcn_mfma_f32_16x16x32_bf16(qf[mt], kf[ntl], z4, 0,0,0);
        #pragma unroll
        for (int r=0; r<4; ++r){
          float p = __expf(sa[r]*scale);
          lr[mt*4+r] += p;
          PB[pbase + (mt*16+quad*4+r)*40 + ntl*16+lo] = f2b(p);
        }
      }
    }
    // PV: A = P (LDS), B = V^T (LDS)
    bf16x8 vf[2];
    #pragma unroll
    for (int nc=0; nc<2; ++nc)
      vf[nc] = *(const bf16x8*)&VT[(nc*16+lo)*264 + ts*32 + quad*8];
    #pragma unroll
    for (int mt=0; mt<4; ++mt){
      bf16x8 paf = *(const bf16x8*)&PB[pbase + (mt*16+lo)*40 + quad*8];
      #pragma unroll
      for (int nc=0; nc<2; ++nc)
        o_acc[mt][nc] = __builtin_amdgcn_mfma_f32_16x16x32_bf16(paf, vf[nc], o_acc[mt][nc], 0,0,0);
    }
  }
  // reduce l across the 16 cols (lanes lo 0..15 within quad group)
  #pragma unroll
  for (int i=0;i<16;++i){
    float v = lr[i];
    v += __shfl_xor(v, 1);
    v += __shfl_xor(v, 2);
    v += __shfl_xor(v, 4);
    v += __shfl_xor(v, 8);
    lr[i] = 1.0f / v;
  }
  // scrambled write (raw-reshape permutation), fp32 into d_out
  int so = 32*h + (l>>3);
  int lob = (l&7)*32;
  #pragma unroll
  for (int mt=0; mt<4; ++mt)
    #pragma unroll
    for (int nc=0; nc<2; ++nc)
      #pragma unroll
      for (int r=0; r<4; ++r){
        int s = m0 + mt*16 + quad*4 + r;
        int c = nc*16 + lo;
        float val = o_acc[mt][nc][r] * lr[mt*4+r];
        int lo2 = lob + (s>>3);
        int hc  = (s&7)*32 + c;
        outp[((size_t)so*256 + lo2)*256 + hc] = val;
      }
}

// ---- K4: fused gate GEMM + sigmoid gating + out-projection (R5 proven) ----
// osc lives in d_out rows r0..r0+63; block reads exactly the rows it later
// overwrites, with a barrier between last read and first write.
__global__ __launch_bounds__(256) void k_out(const u16* __restrict__ mnb,
    const float* __restrict__ wg, const float* __restrict__ bg,
    const float* __restrict__ wo, const float* __restrict__ bo,
    float* __restrict__ outp){
  __shared__ float mns[64*256];    // 64 KB staged mn rows (fp32)
  __shared__ float gst[64][65];    // gated k-tile
  int r0 = blockIdx.x*64;
  int s0 = r0>>8, l0 = r0&255;
  int tid = threadIdx.x;
  int tx = tid&15, ty = tid>>4;

  // stage mn rows from bf16 mnb: mns[rL][cm] = mnb[l0+rL][s0][cm]
  #pragma unroll
  for (int i=0;i<16;++i){
    int e  = i*256 + tid;          // ushort4 index
    int rL = e>>6, c4 = e&63;
    ushort4 mv = *(const ushort4*)&mnb[(((size_t)(l0+rL))*256 + s0)*256 + c4*4];
    *(float4*)&mns[rL*256 + c4*4] =
        make_float4(b2f(mv.x), b2f(mv.y), b2f(mv.z), b2f(mv.w));
  }
  __syncthreads();

  float accC[4][16];
  #pragma unroll
  for (int tc=0; tc<4; ++tc){
    float4 bb = *(const float4*)&bo[tc*64 + tx*4];
    #pragma unroll
    for (int ii=0;ii<4;++ii){
      accC[ii][tc*4+0]=bb.x; accC[ii][tc*4+1]=bb.y;
      accC[ii][tc*4+2]=bb.z; accC[ii][tc*4+3]=bb.w;
    }
  }

  for (int c0=0; c0<256; c0+=64){   // gate col-tile == C k-tile
    int j0 = c0 + tx*4;
    float accB[4][4];
    #pragma unroll
    for (int i=0;i<4;++i){ accB[i][0]=0.f; accB[i][1]=0.f; accB[i][2]=0.f; accB[i][3]=0.f; }
    for (int k=0;k<256;++k){
      float4 w4 = *(const float4*)&wg[k*256 + j0];
      #pragma unroll
      for (int ii=0;ii<4;++ii){
        float xv = mns[(ty*4+ii)*256 + k];
        accB[ii][0]+=xv*w4.x; accB[ii][1]+=xv*w4.y;
        accB[ii][2]+=xv*w4.z; accB[ii][3]+=xv*w4.w;
      }
    }
    float4 bgv = *(const float4*)&bg[j0];
    float gt[4][4];
    #pragma unroll
    for (int ii=0;ii<4;++ii){
      int r = r0 + ty*4 + ii;
      float4 ov = *(const float4*)&outp[(size_t)r*256 + j0];   // osc read
      gt[ii][0] = ov.x / (1.f + __expf(-(accB[ii][0]+bgv.x)));
      gt[ii][1] = ov.y / (1.f + __expf(-(accB[ii][1]+bgv.y)));
      gt[ii][2] = ov.z / (1.f + __expf(-(accB[ii][2]+bgv.z)));
      gt[ii][3] = ov.w / (1.f + __expf(-(accB[ii][3]+bgv.w)));
    }
    __syncthreads();   // previous gst consumers done
    #pragma unroll
    for (int ii=0;ii<4;++ii){
      gst[ty*4+ii][tx*4+0]=gt[ii][0]; gst[ty*4+ii][tx*4+1]=gt[ii][1];
      gst[ty*4+ii][tx*4+2]=gt[ii][2]; gst[ty*4+ii][tx*4+3]=gt[ii][3];
    }
    __syncthreads();   // tile visible
    for (int kk=0; kk<64; ++kk){
      int kG = c0 + kk;
      float xv0 = gst[ty*4+0][kk];
      float xv1 = gst[ty*4+1][kk];
      float xv2 = gst[ty*4+2][kk];
      float xv3 = gst[ty*4+3][kk];
      #pragma unroll
      for (int tc=0; tc<4; ++tc){
        float4 w4 = *(const float4*)&wo[kG*256 + tc*64 + tx*4];
        accC[0][tc*4+0]+=xv0*w4.x; accC[0][tc*4+1]+=xv0*w4.y; accC[0][tc*4+2]+=xv0*w4.z; accC[0][tc*4+3]+=xv0*w4.w;
        accC[1][tc*4+0]+=xv1*w4.x; accC[1][tc*4+1]+=xv1*w4.y; accC[1][tc*4+2]+=xv1*w4.z; accC[1][tc*4+3]+=xv1*w4.w;
        accC[2][tc*4+0]+=xv2*w4.x; accC[2][tc*4+1]+=xv2*w4.y; accC[2][tc*4+2]+=xv2*w4.z; accC[2][tc*4+3]+=xv2*w4.w;
        accC[3][tc*4+0]+=xv3*w4.x; accC[3][tc*4+1]+=xv3*w4.y; accC[3][tc*4+2]+=xv3*w4.z; accC[3][tc*4+3]+=xv3*w4.w;
      }
    }
  }
  __syncthreads();   // ALL osc reads complete before overwriting rows
  #pragma unroll
  for (int ii=0;ii<4;++ii){
    size_t r = r0 + ty*4 + ii;
    #pragma unroll
    for (int tc=0; tc<4; ++tc){
      int j0 = tc*64 + tx*4;
      *(float4*)&outp[r*256 + j0] = make_float4(accC[ii][tc*4+0], accC[ii][tc*4+1],
                                                accC[ii][tc*4+2], accC[ii][tc*4+3]);
    }
  }
}

extern "C" void kernel_launch(void* const* d_in, const int* in_sizes, int n_in,
                              void* d_out, int out_size, void* d_ws, size_t ws_size,
                              hipStream_t stream){
  const float* m  = (const float*)d_in[0];
  const float* lw = (const float*)d_in[1];
  const float* lb = (const float*)d_in[2];
  const float* wq = (const float*)d_in[3];
  const float* wk = (const float*)d_in[4];
  const float* wv = (const float*)d_in[5];
  const float* wg = (const float*)d_in[6];
  const float* bg = (const float*)d_in[7];
  const float* wo = (const float*)d_in[8];
  const float* bo = (const float*)d_in[9];

  // ws: mnb bf16 [l,s,cm] 32MiB | Yq | Yk | Yv bf16 [l,s,hc] 32MiB each = 128MiB
  u16* ws0 = (u16*)d_ws;
  const size_t BUF = (size_t)16777216;
  u16* mnb = ws0;
  u16* Yq  = ws0 + BUF;
  u16* Yk  = ws0 + 2*BUF;
  u16* Yv  = ws0 + 3*BUF;
  float* out = (float*)d_out;

  k_ln  <<<65536,           256, 0, stream>>>(m, lw, lb, mnb);
  k_qkv <<<dim3(256,3,2),   256, 0, stream>>>(mnb, wq, wk, wv, Yq, Yk, Yv);
  k_attn<<<2048,            256, 0, stream>>>(Yq, Yk, Yv, out);
  k_out <<<1024,            256, 0, stream>>>(mnb, wg, bg, wo, bo, out);
}

// Round 7
// 391.375 us; speedup vs baseline: 4.4792x; 2.0863x over previous
//
#include <hip/hip_runtime.h>

typedef unsigned short u16;
typedef __attribute__((ext_vector_type(8))) short bf16x8;   // 8 bf16 = 4 VGPR
typedef __attribute__((ext_vector_type(4))) float f32x4;

__device__ __forceinline__ float b2f(u16 u){ return __uint_as_float(((unsigned int)u)<<16); }
__device__ __forceinline__ u16 f2b(float f){
  unsigned int u = __float_as_uint(f);
  u += 0x7fffu + ((u>>16)&1u);          // round-to-nearest-even
  return (u16)(u>>16);
}

// ---- K1: LayerNorm over c_m -> bf16 mnb [l, s, cm] ----
__global__ __launch_bounds__(256) void k_ln(const float* __restrict__ m,
    const float* __restrict__ lw, const float* __restrict__ lb,
    u16* __restrict__ mnb){
  int row = blockIdx.x;            // s*256 + l
  int s = row>>8, l = row&255;
  int tid = threadIdx.x;
  float x = m[(size_t)row*256 + tid];
  float s1 = x, s2 = x*x;
  #pragma unroll
  for (int off=32; off>0; off>>=1){
    s1 += __shfl_down(s1, off);
    s2 += __shfl_down(s2, off);
  }
  __shared__ float red[10];
  int wv = tid>>6, ln = tid&63;
  if (ln==0){ red[wv]=s1; red[4+wv]=s2; }
  __syncthreads();
  if (tid==0){
    float a = red[0]+red[1]+red[2]+red[3];
    float c = red[4]+red[5]+red[6]+red[7];
    float mu  = a*(1.0f/256.0f);
    float var = c*(1.0f/256.0f) - mu*mu;
    red[8]=mu; red[9]=rsqrtf(var + 1e-5f);
  }
  __syncthreads();
  float mu=red[8], inv=red[9];
  mnb[((size_t)l*256 + s)*256 + tid] = f2b((x-mu)*inv*lw[tid] + lb[tid]);
}

// ---- K2: MFMA QKV projection. grid (l=256, z=3, nhalf=2) ----
__global__ __launch_bounds__(256,2) void k_qkv(const u16* __restrict__ mnb,
    const float* __restrict__ wq, const float* __restrict__ wk,
    const float* __restrict__ wv,
    u16* __restrict__ Yq, u16* __restrict__ Yk, u16* __restrict__ Yv){
  __shared__ u16 WtS[128*264];     // W^T half: [n 128][cm 256], stride 264
  int l = blockIdx.x, z = blockIdx.y, n0 = blockIdx.z*128;
  const float* W = (z==0)?wq:(z==1)?wk:wv;
  u16* Y = (z==0)?Yq:(z==1)?Yk:Yv;
  int tid = threadIdx.x;
  int lane = tid&63, wid = tid>>6, quad = lane>>4, lo = lane&15;

  int cidx = tid&127, half = tid>>7;
  for (int i=0;i<16;++i){
    u16 tmp[8];
    #pragma unroll
    for (int j=0;j<8;++j){
      int cm = half*128 + i*8 + j;
      tmp[j] = f2b(W[cm*256 + n0 + cidx]);
    }
    *(ushort4*)&WtS[cidx*264 + half*128 + i*8]     = *(ushort4*)&tmp[0];
    *(ushort4*)&WtS[cidx*264 + half*128 + i*8 + 4] = *(ushort4*)&tmp[4];
  }
  __syncthreads();

  int m0 = wid*64;
  f32x4 acc[4][8];
  f32x4 z4 = {0.f,0.f,0.f,0.f};
  #pragma unroll
  for (int a=0;a<4;++a)
    #pragma unroll
    for (int b=0;b<8;++b) acc[a][b]=z4;

  const u16* Abase = mnb + (size_t)l*65536;
  for (int ks=0; ks<8; ++ks){
    bf16x8 af[4];
    #pragma unroll
    for (int mt=0; mt<4; ++mt)
      af[mt] = *(const bf16x8*)(Abase + (size_t)(m0+mt*16+lo)*256 + ks*32 + quad*8);
    bf16x8 bf[8];
    #pragma unroll
    for (int nt=0; nt<8; ++nt)
      bf[nt] = *(const bf16x8*)&WtS[(nt*16+lo)*264 + ks*32 + quad*8];
    #pragma unroll
    for (int mt=0; mt<4; ++mt)
      #pragma unroll
      for (int nt=0; nt<8; ++nt)
        acc[mt][nt] = __builtin_amdgcn_mfma_f32_16x16x32_bf16(af[mt], bf[nt], acc[mt][nt], 0,0,0);
  }
  u16* Ybase = Y + (size_t)l*65536;
  #pragma unroll
  for (int mt=0; mt<4; ++mt)
    #pragma unroll
    for (int nt=0; nt<8; ++nt)
      #pragma unroll
      for (int r=0; r<4; ++r){
        int s  = m0 + mt*16 + quad*4 + r;
        int hc = n0 + nt*16 + lo;
        Ybase[(size_t)s*256 + hc] = f2b(acc[mt][nt][r]);
      }
}

// ---- K3: MFMA attention per (l,h); single pass, no max (|logit| small) ----
__global__ __launch_bounds__(256,2) void k_attn(const u16* __restrict__ Yq,
    const u16* __restrict__ Yk, const u16* __restrict__ Yv,
    float* __restrict__ outp){
  __shared__ u16 VT[32*264];       // V^T [c 32][t 256] stride 264
  __shared__ u16 PB[4*64*40];      // per-wave P [64 m][32 t] stride 40
  int bx = blockIdx.x;
  int l = bx>>3, h = bx&7;
  int tid = threadIdx.x;
  int lane = tid&63, wid = tid>>6, quad = lane>>4, lo = lane&15;
  const size_t tile = ((size_t)l*256)*256 + h*32;
  const u16* qb = Yq + tile;
  const u16* kb = Yk + tile;
  const u16* vb = Yv + tile;

  {
    int t = tid;
    const u16* vp = vb + (size_t)t*256;
    #pragma unroll
    for (int c4=0; c4<8; ++c4){
      ushort4 vv = *(const ushort4*)(vp + c4*4);
      VT[(c4*4+0)*264 + t] = vv.x;
      VT[(c4*4+1)*264 + t] = vv.y;
      VT[(c4*4+2)*264 + t] = vv.z;
      VT[(c4*4+3)*264 + t] = vv.w;
    }
  }

  int m0 = wid*64;
  int pbase = wid*64*40;
  bf16x8 qf[4];
  #pragma unroll
  for (int mt=0; mt<4; ++mt)
    qf[mt] = *(const bf16x8*)(qb + (size_t)(m0+mt*16+lo)*256 + quad*8);

  __syncthreads();   // VT ready

  const float scale = 0.17677669529663687f;  // 1/sqrt(32)
  float lr[16];
  #pragma unroll
  for (int i=0;i<16;++i) lr[i]=0.f;
  f32x4 o_acc[4][2];
  f32x4 z4 = {0.f,0.f,0.f,0.f};
  #pragma unroll
  for (int a=0;a<4;++a){ o_acc[a][0]=z4; o_acc[a][1]=z4; }

  for (int ts=0; ts<8; ++ts){
    bf16x8 kf[2];
    #pragma unroll
    for (int ntl=0; ntl<2; ++ntl)
      kf[ntl] = *(const bf16x8*)(kb + (size_t)(ts*32+ntl*16+lo)*256 + quad*8);
    #pragma unroll
    for (int mt=0; mt<4; ++mt){
      #pragma unroll
      for (int ntl=0; ntl<2; ++ntl){
        f32x4 sa = __builtin_amdgcn_mfma_f32_16x16x32_bf16(qf[mt], kf[ntl], z4, 0,0,0);
        #pragma unroll
        for (int r=0; r<4; ++r){
          float p = __expf(sa[r]*scale);
          lr[mt*4+r] += p;
          PB[pbase + (mt*16+quad*4+r)*40 + ntl*16+lo] = f2b(p);
        }
      }
    }
    bf16x8 vf[2];
    #pragma unroll
    for (int nc=0; nc<2; ++nc)
      vf[nc] = *(const bf16x8*)&VT[(nc*16+lo)*264 + ts*32 + quad*8];
    #pragma unroll
    for (int mt=0; mt<4; ++mt){
      bf16x8 paf = *(const bf16x8*)&PB[pbase + (mt*16+lo)*40 + quad*8];
      #pragma unroll
      for (int nc=0; nc<2; ++nc)
        o_acc[mt][nc] = __builtin_amdgcn_mfma_f32_16x16x32_bf16(paf, vf[nc], o_acc[mt][nc], 0,0,0);
    }
  }
  #pragma unroll
  for (int i=0;i<16;++i){
    float v = lr[i];
    v += __shfl_xor(v, 1);
    v += __shfl_xor(v, 2);
    v += __shfl_xor(v, 4);
    v += __shfl_xor(v, 8);
    lr[i] = 1.0f / v;
  }
  int so = 32*h + (l>>3);
  int lob = (l&7)*32;
  #pragma unroll
  for (int mt=0; mt<4; ++mt)
    #pragma unroll
    for (int nc=0; nc<2; ++nc)
      #pragma unroll
      for (int r=0; r<4; ++r){
        int s = m0 + mt*16 + quad*4 + r;
        int c = nc*16 + lo;
        float val = o_acc[mt][nc][r] * lr[mt*4+r];
        int lo2 = lob + (s>>3);
        int hc  = (s&7)*32 + c;
        outp[((size_t)so*256 + lo2)*256 + hc] = val;
      }
}

// ---- K4: MFMA gate GEMM: P = sigmoid(mn@wg + bg) * osc, bf16 -> Pbuf ----
// grid (s=256, nhalf=2). Block rows: r = s*256 + l, l = 0..255.
__global__ __launch_bounds__(256,2) void k_gate(const u16* __restrict__ mnb,
    const float* __restrict__ wg, const float* __restrict__ bg,
    const float* __restrict__ osc, u16* __restrict__ P){
  __shared__ u16 WtS[128*264];
  int s = blockIdx.x, n0 = blockIdx.y*128;
  int tid = threadIdx.x;
  int lane = tid&63, wid = tid>>6, quad = lane>>4, lo = lane&15;

  int cidx = tid&127, half = tid>>7;
  for (int i=0;i<16;++i){
    u16 tmp[8];
    #pragma unroll
    for (int j=0;j<8;++j){
      int cm = half*128 + i*8 + j;
      tmp[j] = f2b(wg[cm*256 + n0 + cidx]);
    }
    *(ushort4*)&WtS[cidx*264 + half*128 + i*8]     = *(ushort4*)&tmp[0];
    *(ushort4*)&WtS[cidx*264 + half*128 + i*8 + 4] = *(ushort4*)&tmp[4];
  }
  __syncthreads();

  int m0 = wid*64;
  f32x4 acc[4][8];
  f32x4 z4 = {0.f,0.f,0.f,0.f};
  #pragma unroll
  for (int a=0;a<4;++a)
    #pragma unroll
    for (int b=0;b<8;++b) acc[a][b]=z4;

  for (int ks=0; ks<8; ++ks){
    bf16x8 af[4];
    #pragma unroll
    for (int mt=0; mt<4; ++mt)     // A row = mn[s, l=m] = mnb[l*256+s]
      af[mt] = *(const bf16x8*)(mnb + (size_t)(m0+mt*16+lo)*65536 + s*256 + ks*32 + quad*8);
    bf16x8 bf[8];
    #pragma unroll
    for (int nt=0; nt<8; ++nt)
      bf[nt] = *(const bf16x8*)&WtS[(nt*16+lo)*264 + ks*32 + quad*8];
    #pragma unroll
    for (int mt=0; mt<4; ++mt)
      #pragma unroll
      for (int nt=0; nt<8; ++nt)
        acc[mt][nt] = __builtin_amdgcn_mfma_f32_16x16x32_bf16(af[mt], bf[nt], acc[mt][nt], 0,0,0);
  }
  #pragma unroll
  for (int nt=0; nt<8; ++nt){
    int n = n0 + nt*16 + lo;
    float bgn = bg[n];
    #pragma unroll
    for (int mt=0; mt<4; ++mt)
      #pragma unroll
      for (int r=0; r<4; ++r){
        int l = m0 + mt*16 + quad*4 + r;
        size_t rr = (size_t)s*256 + l;
        float g = 1.f/(1.f + __expf(-(acc[mt][nt][r] + bgn)));
        P[rr*256 + n] = f2b(g * osc[rr*256 + n]);
      }
  }
}

// ---- K5: MFMA out projection: out = P @ wo + bo (fp32 -> d_out) ----
// grid (rblk=256, nhalf=2). Block rows: r0 = bx*256.
__global__ __launch_bounds__(256,2) void k_proj(const u16* __restrict__ P,
    const float* __restrict__ wo, const float* __restrict__ bo,
    float* __restrict__ outp){
  __shared__ u16 WtS[128*264];
  int r0 = blockIdx.x*256, n0 = blockIdx.y*128;
  int tid = threadIdx.x;
  int lane = tid&63, wid = tid>>6, quad = lane>>4, lo = lane&15;

  int cidx = tid&127, half = tid>>7;
  for (int i=0;i<16;++i){
    u16 tmp[8];
    #pragma unroll
    for (int j=0;j<8;++j){
      int cm = half*128 + i*8 + j;
      tmp[j] = f2b(wo[cm*256 + n0 + cidx]);
    }
    *(ushort4*)&WtS[cidx*264 + half*128 + i*8]     = *(ushort4*)&tmp[0];
    *(ushort4*)&WtS[cidx*264 + half*128 + i*8 + 4] = *(ushort4*)&tmp[4];
  }
  __syncthreads();

  int m0 = wid*64;
  f32x4 acc[4][8];
  f32x4 z4 = {0.f,0.f,0.f,0.f};
  #pragma unroll
  for (int a=0;a<4;++a)
    #pragma unroll
    for (int b=0;b<8;++b) acc[a][b]=z4;

  const u16* Abase = P + (size_t)r0*256;
  for (int ks=0; ks<8; ++ks){
    bf16x8 af[4];
    #pragma unroll
    for (int mt=0; mt<4; ++mt)
      af[mt] = *(const bf16x8*)(Abase + (size_t)(m0+mt*16+lo)*256 + ks*32 + quad*8);
    bf16x8 bf[8];
    #pragma unroll
    for (int nt=0; nt<8; ++nt)
      bf[nt] = *(const bf16x8*)&WtS[(nt*16+lo)*264 + ks*32 + quad*8];
    #pragma unroll
    for (int mt=0; mt<4; ++mt)
      #pragma unroll
      for (int nt=0; nt<8; ++nt)
        acc[mt][nt] = __builtin_amdgcn_mfma_f32_16x16x32_bf16(af[mt], bf[nt], acc[mt][nt], 0,0,0);
  }
  #pragma unroll
  for (int nt=0; nt<8; ++nt){
    int n = n0 + nt*16 + lo;
    float bon = bo[n];
    #pragma unroll
    for (int mt=0; mt<4; ++mt)
      #pragma unroll
      for (int r=0; r<4; ++r){
        size_t rr = (size_t)r0 + m0 + mt*16 + quad*4 + r;
        outp[rr*256 + n] = acc[mt][nt][r] + bon;
      }
  }
}

extern "C" void kernel_launch(void* const* d_in, const int* in_sizes, int n_in,
                              void* d_out, int out_size, void* d_ws, size_t ws_size,
                              hipStream_t stream){
  const float* m  = (const float*)d_in[0];
  const float* lw = (const float*)d_in[1];
  const float* lb = (const float*)d_in[2];
  const float* wq = (const float*)d_in[3];
  const float* wk = (const float*)d_in[4];
  const float* wv = (const float*)d_in[5];
  const float* wg = (const float*)d_in[6];
  const float* bg = (const float*)d_in[7];
  const float* wo = (const float*)d_in[8];
  const float* bo = (const float*)d_in[9];

  // ws: mnb bf16 [l,s,cm] 32MiB | Yq | Yk | Yv bf16 32MiB each = 128MiB
  // Pbuf (gated, bf16 [s*256+l, hc]) aliases Yq (dead after k_attn).
  u16* ws0 = (u16*)d_ws;
  const size_t BUF = (size_t)16777216;
  u16* mnb  = ws0;
  u16* Yq   = ws0 + BUF;
  u16* Yk   = ws0 + 2*BUF;
  u16* Yv   = ws0 + 3*BUF;
  u16* Pbuf = Yq;
  float* out = (float*)d_out;

  k_ln  <<<65536,           256, 0, stream>>>(m, lw, lb, mnb);
  k_qkv <<<dim3(256,3,2),   256, 0, stream>>>(mnb, wq, wk, wv, Yq, Yk, Yv);
  k_attn<<<2048,            256, 0, stream>>>(Yq, Yk, Yv, out);
  k_gate<<<dim3(256,2),     256, 0, stream>>>(mnb, wg, bg, out, Pbuf);
  k_proj<<<dim3(256,2),     256, 0, stream>>>(Pbuf, wo, bo, out);
}